// Round 5
// baseline (6131.355 us; speedup 1.0000x reference)
//
#include <hip/hip_runtime.h>
#include <hip/hip_bf16.h>

#define Bn   1024
#define Tn   730
#define INn  64
#define Hn   512
#define Kn   576      // INn + Hn
#define KCn  36       // K chunks of 16
#define G4n  2048     // 4*Hn

typedef __bf16 bf16x8 __attribute__((ext_vector_type(8)));
typedef float  f32x4  __attribute__((ext_vector_type(4)));
typedef float  f32x16 __attribute__((ext_vector_type(16)));

// ---------------- weight pre-pack: Wc[row][k] bf16, row = gate*512+j, k over [x|h] ----------
__global__ void convert_weights(const float* __restrict__ Wih,
                                const float* __restrict__ Whh,
                                __bf16* __restrict__ Wc) {
    int idx = blockIdx.x * 256 + threadIdx.x;
    if (idx >= G4n * Kn) return;
    int row = idx / Kn;
    int k   = idx - row * Kn;
    float v = (k < INn) ? Wih[row * INn + k] : Whh[row * Hn + (k - INn)];
    Wc[idx] = (__bf16)v;
}

__device__ __forceinline__ float sigf(float x)   { return 1.0f / (1.0f + __expf(-x)); }
__device__ __forceinline__ float tanhf_f(float x){ return 2.0f * sigf(2.0f * x) - 1.0f; }

__device__ __forceinline__ bf16x8 cvt_x8(const float* xp) {
    f32x4 lo = *(const f32x4*)xp;
    f32x4 hi = *(const f32x4*)(xp + 4);
    bf16x8 v;
    v[0]=(__bf16)lo[0]; v[1]=(__bf16)lo[1]; v[2]=(__bf16)lo[2]; v[3]=(__bf16)lo[3];
    v[4]=(__bf16)hi[0]; v[5]=(__bf16)hi[1]; v[6]=(__bf16)hi[2]; v[7]=(__bf16)hi[3];
    return v;
}

// ---------------- persistent LSTM scan ----------------
// 512 blocks x 256 threads (2 blocks/CU). Block = (mi: 32 batch rows) x (nj: 32 j-cols).
// Wave w (of 4) = gate w, all 32 cols: one 32x32 MFMA tile; weights resident in
// 144 VGPRs (36 x bf16x8). c state in 4 VGPRs/thread.
// MFMA 32x32x16_bf16: A[m=lane&31][k=(lane>>5)*8+e]; B[k][n=lane&31] same k-split;
// C/D: col=lane&31, row=(reg&3)+8*(reg>>2)+4*(lane>>5)  [guide-verified m74/m101].
// Cross-block dep only among 16 blocks sharing mi. Coherence: h + flags move via
// RELAXED agent-scope atomics (sc1, per-line, no cache-wide wb/inv); ordering via
// __syncthreads (drains vmcnt(0) before s_barrier) -> h at IC before flag set.
__global__ __launch_bounds__(256, 2) void lstm_persist(
    const float* __restrict__ xd,     // [B,T,IN]
    const float* __restrict__ bias,   // [4H]
    const __bf16* __restrict__ Wc,    // [4H][Kn]
    __bf16* __restrict__ h0,          // [B,H] buffer A (final h lands here)
    __bf16* __restrict__ h1,          // [B,H] buffer B
    unsigned int* __restrict__ flags) // 32 groups x 16 blocks (64B line per group)
{
    // LDS: aTile 36 kc x 64 lanes x 16B = 36864 B; zBuf 16 x 64 x 16B = 16384 B
    __shared__ __align__(16) char smem[36864 + 16384];
    bf16x8* aTile = (bf16x8*)smem;
    f32x4*  zBuf  = (f32x4*)(smem + 36864);
    float*  zf32  = (float*)(smem + 36864);

    const int blk  = blockIdx.x;
    const int xcd  = blk & 7;
    const int slot = blk >> 3;            // 0..63
    const int mi   = xcd * 4 + (slot & 3);// 0..31  (group: 16 blocks, XCD-local)
    const int nj   = slot >> 2;           // 0..15
    const int m0   = mi << 5;             // 32 rows
    const int j0   = nj << 5;             // 32 j-cols

    const int tid  = threadIdx.x;
    const int wave = tid >> 6;            // 0..3 = gate
    const int lane = tid & 63;
    const int l32  = lane & 31;
    const int q2   = lane >> 5;

    // ---- resident weights: gate x 32 cols, 36 k-chunks (b128 each) ----
    bf16x8 wreg[36];
    {
        const __bf16* wbase = Wc + (size_t)(wave * Hn + j0 + l32) * Kn + q2 * 8;
        #pragma unroll
        for (int kc = 0; kc < 36; ++kc)
            wreg[kc] = *(const bf16x8*)(wbase + kc * 16);
    }

    // ---- pointwise ownership: thread -> (1 row, 4 consecutive cols) ----
    const int prow = tid >> 3;            // 0..31
    const int pc0  = (tid & 7) << 2;      // 0..28
    const int rq_p = prow >> 3;
    const int q2_p = (prow >> 2) & 1;
    const int r3_p = prow & 3;
    const f32x4 bi4 = *(const f32x4*)(bias + j0 + pc0);
    const f32x4 bf4 = *(const f32x4*)(bias + Hn + j0 + pc0);
    const f32x4 bg4 = *(const f32x4*)(bias + 2 * Hn + j0 + pc0);
    const f32x4 bo4 = *(const f32x4*)(bias + 3 * Hn + j0 + pc0);
    float creg[4] = {0.f, 0.f, 0.f, 0.f};

    unsigned int* fl = flags + (mi << 4);
    bool dead = false;

    // ---- pre-stage x(0): 4 kc x 64 lanes = 256 cells, 1/thread ----
    {
        const int laneC = tid & 63;
        const int kc    = tid >> 6;
        const int row   = m0 + (laneC & 31);
        const int k0    = kc * 16 + (laneC >> 5) * 8;
        aTile[kc * 64 + laneC] = cvt_x8(xd + (size_t)row * (Tn * INn) + k0);
    }

    for (int t = 0; t < Tn; ++t) {
        const __bf16* hread  = (t & 1) ? h1 : h0;
        __bf16*       hwrite = (t & 1) ? h0 : h1;

        // ---- A: stage h(t-1) -> aTile kc 4..35 (sc1 loads from IC) ----
        #pragma unroll
        for (int i = 0; i < 8; ++i) {
            const int c     = i * 256 + tid;   // 0..2047
            const int laneC = c & 63;
            const int kch   = c >> 6;          // 0..31
            const int row   = m0 + (laneC & 31);
            const int hcol  = kch * 16 + (laneC >> 5) * 8;
            const unsigned long long* hp =
                (const unsigned long long*)(hread + (size_t)row * Hn + hcol);
            union { unsigned long long u[2]; bf16x8 v8; } cv;
            cv.u[0] = __hip_atomic_load(hp,     __ATOMIC_RELAXED, __HIP_MEMORY_SCOPE_AGENT);
            cv.u[1] = __hip_atomic_load(hp + 1, __ATOMIC_RELAXED, __HIP_MEMORY_SCOPE_AGENT);
            aTile[(kch + 4) * 64 + laneC] = cv.v8;
        }
        __syncthreads();

        // ---- C: MFMA 32x32, weights from regs, A from LDS; 2 acc chains ----
        f32x16 acc0 = {0,0,0,0,0,0,0,0,0,0,0,0,0,0,0,0};
        f32x16 acc1 = {0,0,0,0,0,0,0,0,0,0,0,0,0,0,0,0};
        #pragma unroll
        for (int kc = 0; kc < 36; kc += 2) {
            acc0 = __builtin_amdgcn_mfma_f32_32x32x16_bf16(aTile[kc * 64 + lane],       wreg[kc],     acc0, 0, 0, 0);
            acc1 = __builtin_amdgcn_mfma_f32_32x32x16_bf16(aTile[(kc + 1) * 64 + lane], wreg[kc + 1], acc1, 0, 0, 0);
        }
        const f32x16 acc = acc0 + acc1;

        // ---- E: z-exchange (wave = gate) ----
        #pragma unroll
        for (int rq = 0; rq < 4; ++rq) {
            f32x4 zv = { acc[rq * 4 + 0], acc[rq * 4 + 1], acc[rq * 4 + 2], acc[rq * 4 + 3] };
            zBuf[(wave * 4 + rq) * 64 + lane] = zv;
        }
        __syncthreads();

        // ---- G: gate pointwise; c in regs; h -> global u64 write-through ----
        float z[4][4];
        #pragma unroll
        for (int g = 0; g < 4; ++g) {
            const int base = ((g * 4 + rq_p) * 64 + q2_p * 32 + pc0) * 4 + r3_p;
            #pragma unroll
            for (int cc = 0; cc < 4; ++cc)
                z[g][cc] = zf32[base + cc * 4];
        }
        union { unsigned long long u; __bf16 h[4]; } pk;
        #pragma unroll
        for (int cc = 0; cc < 4; ++cc) {
            const float cn = sigf(z[1][cc] + bf4[cc]) * creg[cc]
                           + sigf(z[0][cc] + bi4[cc]) * tanhf_f(z[2][cc] + bg4[cc]);
            creg[cc] = cn;
            pk.h[cc] = (__bf16)(sigf(z[3][cc] + bo4[cc]) * tanhf_f(cn));
        }
        __hip_atomic_store((unsigned long long*)(hwrite + (size_t)(m0 + prow) * Hn + j0 + pc0),
                           pk.u, __ATOMIC_RELAXED, __HIP_MEMORY_SCOPE_AGENT);

        // ---- H: drain h stores (vmcnt(0) before s_barrier), then publish+overlap+wait ----
        __syncthreads();
        if (t < Tn - 1) {
            if (tid == 0)
                __hip_atomic_store(fl + nj, (unsigned int)(t + 1),
                                   __ATOMIC_RELAXED, __HIP_MEMORY_SCOPE_AGENT);
            // J: stage x(t+1) during barrier propagation (aTile x-region is idle)
            {
                const int laneC = tid & 63;
                const int kc    = tid >> 6;
                const int row   = m0 + (laneC & 31);
                const int k0    = kc * 16 + (laneC >> 5) * 8;
                aTile[kc * 64 + laneC] =
                    cvt_x8(xd + (size_t)row * (Tn * INn) + (size_t)(t + 1) * INn + k0);
            }
            // K: wave 0 polls the group's 16 flags
            if (tid < 64) {
                const unsigned int target = (unsigned int)(t + 1);
                int spins = 0;
                while (!dead) {
                    unsigned int v = (lane < 16)
                        ? __hip_atomic_load(fl + lane, __ATOMIC_RELAXED, __HIP_MEMORY_SCOPE_AGENT)
                        : target;
                    if (__all(v >= target)) break;
                    __builtin_amdgcn_s_sleep(1);
                    if (++spins > 200000) dead = true;   // hang -> fast wrong-answer
                }
            }
            __syncthreads();
        }
    }
}

// ---------------- head: out[b] = relu(dot(h_T[b], Wl) + bl) ----------------
__global__ void head_kernel(const __bf16* __restrict__ h, const float* __restrict__ Wl,
                            const float* __restrict__ bl, float* __restrict__ out) {
    const int b = blockIdx.x;
    const int lane = threadIdx.x;  // 64 threads
    const __bf16* hp = h + (size_t)b * Hn;
    float s = 0.f;
    #pragma unroll
    for (int j = lane; j < Hn; j += 64) s += (float)hp[j] * Wl[j];
    #pragma unroll
    for (int off = 32; off > 0; off >>= 1) s += __shfl_down(s, off, 64);
    if (lane == 0) out[b] = fmaxf(s + bl[0], 0.0f);
}

extern "C" void kernel_launch(void* const* d_in, const int* in_sizes, int n_in,
                              void* d_out, int out_size, void* d_ws, size_t ws_size,
                              hipStream_t stream) {
    const float* xd  = (const float*)d_in[0];
    const float* Wih = (const float*)d_in[1];
    const float* Whh = (const float*)d_in[2];
    const float* b   = (const float*)d_in[3];
    const float* Wl  = (const float*)d_in[4];
    const float* bl  = (const float*)d_in[5];
    float* out = (float*)d_out;

    // ws layout:
    //   Wc    bf16 [2048][576] : 2,359,296 B
    //   h0    bf16 [1024][512] : 1,048,576 B
    //   h1    bf16 [1024][512] : 1,048,576 B
    //   flags u32  [32][16]    : 2,048 B
    char* ws = (char*)d_ws;
    __bf16* Wc = (__bf16*)ws;
    __bf16* h0 = (__bf16*)(ws + 2359296);
    __bf16* h1 = (__bf16*)(ws + 2359296 + 1048576);
    unsigned int* flags = (unsigned int*)(ws + 2359296 + 2 * 1048576);

    hipMemsetAsync(h0, 0, 1048576, stream);   // t=0 reads h0 as zeros
    hipMemsetAsync(flags, 0, 2048, stream);   // per-block step flags

    const int total = G4n * Kn;
    convert_weights<<<(total + 255) / 256, 256, 0, stream>>>(Wih, Whh, Wc);

    lstm_persist<<<512, 256, 0, stream>>>(xd, b, Wc, h0, h1, flags);

    // t=729 (odd) writes h0 -> final hidden state is in h0
    head_kernel<<<Bn, 64, 0, stream>>>(h0, Wl, bl, out);
}